// Round 16
// baseline (93.911 us; speedup 1.0000x reference)
//
#include <hip/hip_runtime.h>

#define NVEC (64*64*64)   // 262144 vectors
#define KCB 1024          // codebook size
#define DIM 64            // codebook dim
#define NBATCH 8          // 64-vector batches per A-block
#define AGRID 512         // NVEC / (NBATCH*64) -> 2 blocks/CU (512-thr blocks pack 2/CU)
#define BVEC 256          // vectors per B-block
#define BGRID (NVEC / BVEC)
#define NSLOT 32          // global count-accumulation slots

typedef __attribute__((ext_vector_type(8))) short s16x8;   // 8 x bf16
typedef __attribute__((ext_vector_type(4))) float f32x4;

#define MFMA16(A, B, C) __builtin_amdgcn_mfma_f32_16x16x32_bf16((A), (B), (C), 0, 0, 0)

// ws layout (bytes):
//       0 : float cnf[1024]            (ends 4096)
//    4096 : ushort cbA[64][2][64][8]   A-frag bf16(-2c), 131072 B (ends 135168)
//  135168 : uint pbuf[NVEC]            packed (score|idx), 1 MB (ends 1183744)
// 1183744 : float xnpart[512]          per-A-block sum ||x||^2
// 1185792 : float scorepart[1024]      per-B-block sum min-scores
// 1189888 : uint slots[32][1024]       count accumulators (zeroed by vq_prep)

__global__ __launch_bounds__(256) void vq_prep(const float* __restrict__ cb,
                                               unsigned short* __restrict__ cbA,
                                               float* __restrict__ cnf,
                                               unsigned int* __restrict__ slots) {
    int q = blockIdx.x * 256 + threadIdx.x;      // 0..8191
    ((int4*)slots)[q] = int4{0, 0, 0, 0};         // zero all 32*1024 uints
    int t = q >> 7;
    int h = (q >> 6) & 1;
    int l = q & 63;
    int m = t * 16 + (l & 15);
    int d0 = h * 32 + ((l >> 4) & 3) * 8;
    const float* row = cb + (size_t)m * DIM + d0;
    unsigned short* dst = cbA + (size_t)q * 8;
    #pragma unroll
    for (int j = 0; j < 8; ++j) {
        float f = -2.0f * row[j];
        unsigned u = __float_as_uint(f);
        dst[j] = (unsigned short)((u + 0x7fffu + ((u >> 16) & 1u)) >> 16);  // RNE bf16
    }
    if (q < KCB) {
        const float* r2 = cb + (size_t)q * DIM;
        double s = 0.0;
        for (int d = 0; d < DIM; ++d) { double c = (double)r2[d]; s = fma(c, c, s); }
        cnf[q] = (float)s;
    }
}

// Phase A: 512-thread blocks (8 waves) -- 2 independent barrier domains per CU.
// Wave wv holds 128 codes register-resident; block scores 512 vectors against
// ALL 1024 codes (x read ONCE); emits 1 packed u32 per vector. No gather here.
__global__ __launch_bounds__(512, 4) void vq_mainA(const float* __restrict__ inp,
                                                   const unsigned short* __restrict__ cbA,
                                                   const float* __restrict__ cnf,
                                                   unsigned int* __restrict__ pbuf,
                                                   float* __restrict__ xnpart) {
    __shared__ unsigned short xf[2][512][8];   // 64-vec bf16 frags, dbuf, 16 KB
    __shared__ float cnS[KCB];                 // ||c||^2 staged once, 4 KB
    __shared__ float sred[64][9];              // per-vec per-wave packed best
    __shared__ float lossL[8];

    const int tid  = threadIdx.x;
    const int lane = tid & 63;
    const int wv   = tid >> 6;        // wave 0..7 = 128-code slice
    const int l15  = lane & 15;
    const int g    = lane >> 4;
    const int gi   = g * 4;
    const size_t blockbase = (size_t)blockIdx.x * (NBATCH * 64);

    // convert role (all 512 threads): cell tid = (vt*2+h)*64 + l  (R12 mapping)
    const int cvt_vt  = tid >> 7;                        // 0..3
    const int cvt_h   = (tid >> 6) & 1;
    const int cvt_l   = tid & 63;
    const int cvt_vec = cvt_vt * 16 + (cvt_l & 15);      // vec-in-batch 0..63
    const int cvt_d0  = cvt_h * 32 + (cvt_l >> 4) * 8;   // first of its 8 dims

    // stage cnf once (512 threads x 2 floats)
    ((float2*)cnS)[tid] = ((const float2*)cnf)[tid];

    // ---- issue batch-0 x loads first ----
    float4 x0, x1;
    {
        const float* xp = inp + (blockbase + cvt_vec) * DIM + cvt_d0;
        x0 = ((const float4*)xp)[0];
        x1 = ((const float4*)xp)[1];
    }

    // ---- this wave's 128 codes -> registers (stay forever; 64 VGPR) ----
    const s16x8* __restrict__ Ap = (const s16x8*)cbA;
    s16x8 A[8][2];
    #pragma unroll
    for (int tt = 0; tt < 8; ++tt) {
        int Tg = wv * 8 + tt;
        A[tt][0] = Ap[(Tg * 2 + 0) * 64 + lane];
        A[tt][1] = Ap[(Tg * 2 + 1) * 64 + lane];
    }

    float xnacc = 0.0f;

    for (int b = 0; b < NBATCH; ++b) {
        const int buf = b & 1;

        // ---- convert: 8 floats -> one 16B frag cell; accumulate ||x||^2 ----
        {
            float f[8] = {x0.x, x0.y, x0.z, x0.w, x1.x, x1.y, x1.z, x1.w};
            unsigned wq[4];
            #pragma unroll
            for (int p = 0; p < 4; ++p) {
                xnacc = fmaf(f[2*p], f[2*p], xnacc);
                xnacc = fmaf(f[2*p+1], f[2*p+1], xnacc);
                unsigned r;
                asm("v_cvt_pk_bf16_f32 %0, %1, %2" : "=v"(r) : "v"(f[2*p]), "v"(f[2*p+1]));
                wq[p] = r;
            }
            *(int4*)&xf[buf][tid][0] = *(const int4*)wq;
        }
        __syncthreads();   // frags ready (also orders cnS staging before batch 0)

        // ---- issue next batch's x loads; held in regs across MFMA phase ----
        if (b + 1 < NBATCH) {
            const float* xp = inp + (blockbase + (size_t)(b + 1) * 64 + cvt_vec) * DIM + cvt_d0;
            x0 = ((const float4*)xp)[0];
            x1 = ((const float4*)xp)[1];
        }

        // ---- MFMA + argmin: 64 vecs x this wave's 128 codes ----
        #pragma unroll
        for (int vt = 0; vt < 4; ++vt) {
            s16x8 xb0 = *(const s16x8*)&xf[buf][(vt * 2 + 0) * 64 + lane][0];
            s16x8 xb1 = *(const s16x8*)&xf[buf][(vt * 2 + 1) * 64 + lane][0];
            f32x4 acc[8];
            #pragma unroll
            for (int tt = 0; tt < 8; ++tt)
                acc[tt] = *(const f32x4*)(cnS + (wv * 8 + tt) * 16 + gi);  // init = ||c||^2
            #pragma unroll
            for (int tt = 0; tt < 8; ++tt) acc[tt] = MFMA16(A[tt][0], xb0, acc[tt]);
            #pragma unroll
            for (int tt = 0; tt < 8; ++tt) acc[tt] = MFMA16(A[tt][1], xb1, acc[tt]);

            float bv = 3.4e38f;
            #pragma unroll
            for (int tt = 0; tt < 8; ++tt) {
                unsigned cbase = (unsigned)((wv * 8 + tt) * 16 + gi);
                float p0 = __uint_as_float((__float_as_uint(acc[tt][0]) & 0xFFFFFC00u) | cbase);
                float p1 = __uint_as_float((__float_as_uint(acc[tt][1]) & 0xFFFFFC00u) | (cbase + 1));
                float p2 = __uint_as_float((__float_as_uint(acc[tt][2]) & 0xFFFFFC00u) | (cbase + 2));
                float p3 = __uint_as_float((__float_as_uint(acc[tt][3]) & 0xFFFFFC00u) | (cbase + 3));
                float m01;
                asm("v_min3_f32 %0, %1, %2, %3" : "=v"(m01) : "v"(p0), "v"(p1), "v"(p2));
                asm("v_min3_f32 %0, %1, %2, %3" : "=v"(bv) : "v"(m01), "v"(p3), "v"(bv));
            }
            // combine across the 4 lane groups (codes split by g)
            bv = fminf(bv, __shfl_xor(bv, 16));
            bv = fminf(bv, __shfl_xor(bv, 32));
            if (g == 0) sred[vt * 16 + l15][wv] = bv;
        }
        __syncthreads();   // sred ready

        // ---- cross-wave (8) combine -> 1 packed u32 per vector ----
        {
            const int vec = tid >> 3, sl = tid & 7;    // 64 vecs x 8 slots
            float pb = sred[vec][sl];
            pb = fminf(pb, __shfl_xor(pb, 1));
            pb = fminf(pb, __shfl_xor(pb, 2));
            pb = fminf(pb, __shfl_xor(pb, 4));
            if (sl == 0) pbuf[blockbase + (size_t)b * 64 + vec] = __float_as_uint(pb);
        }
        // next convert writes xf[buf^1]; sred rewritten only after next barrier
    }

    // ---- block Sum ||x||^2 -> one partial ----
    #pragma unroll
    for (int off = 32; off > 0; off >>= 1) xnacc += __shfl_xor(xnacc, off);
    if (lane == 0) lossL[wv] = xnacc;
    __syncthreads();
    if (tid == 0) {
        float v = 0.f;
        #pragma unroll
        for (int i = 0; i < 8; ++i) v += lossL[i];
        xnpart[blockIdx.x] = v;
    }
}

// Phase B: streaming -- read packed best, gather code row (L2-hot), write out,
// sum scores, LDS hist -> slots. Pure TLP, no MFMA, no lockstep.
__global__ __launch_bounds__(256) void vq_mainB(const unsigned int* __restrict__ pbuf,
                                                const float* __restrict__ cb,
                                                float* __restrict__ out,
                                                float* __restrict__ scorepart,
                                                unsigned int* __restrict__ slots) {
    __shared__ unsigned int histS[KCB];
    __shared__ float lred[4];
    const int tid = threadIdx.x, lane = tid & 63, wv = tid >> 6;
    #pragma unroll
    for (int i = 0; i < 4; ++i) histS[tid + i * 256] = 0u;
    __syncthreads();

    float sacc = 0.f;
    const size_t vb = (size_t)blockIdx.x * BVEC;
    const float4* cb4 = (const float4*)cb;
    float4* out4 = (float4*)out;

    for (int r = 0; r < BVEC / 16; ++r) {
        const size_t vec = vb + r * 16 + (tid >> 4);
        const int sl = tid & 15;
        float pf = __uint_as_float(pbuf[vec]);       // final packed (score|idx)
        const int bk = (int)(__float_as_uint(pf) & 1023u);
        float4 q = cb4[bk * 16 + sl];
        out4[vec * 16 + sl] = q;
        if (sl == 0) {
            sacc += pf;                               // idx-bit noise ~2e-6 rel
            atomicAdd(&histS[bk], 1u);
        }
    }

    #pragma unroll
    for (int off = 32; off > 0; off >>= 1) sacc += __shfl_xor(sacc, off);
    if (lane == 0) lred[wv] = sacc;
    __syncthreads();
    if (tid == 0) scorepart[blockIdx.x] = lred[0] + lred[1] + lred[2] + lred[3];
    #pragma unroll
    for (int i = 0; i < 4; ++i) {
        unsigned hv = histS[tid + i * 256];
        if (hv) atomicAdd(&slots[(blockIdx.x & (NSLOT - 1)) * KCB + tid + i * 256], hv);
    }
}

__global__ __launch_bounds__(1024) void vq_finalize(float* __restrict__ out,
                                                    const float* __restrict__ scorepart,
                                                    const float* __restrict__ xnpart,
                                                    const unsigned int* __restrict__ slots) {
    __shared__ double red[1024];
    const int tid = threadIdx.x;
    unsigned tot = 0;
    #pragma unroll
    for (int s = 0; s < NSLOT; ++s) tot += slots[s * KCB + tid];
    double p = (double)tot / (double)NVEC;
    double h = p * log(p + 1e-10);
    double ls = (double)scorepart[tid] + (tid < AGRID ? (double)xnpart[tid] : 0.0);

    red[tid] = ls;
    __syncthreads();
    for (int t = 512; t > 0; t >>= 1) {
        if (tid < t) red[tid] += red[tid + t];
        __syncthreads();
    }
    double loss_tot = red[0];
    __syncthreads();
    red[tid] = h;
    __syncthreads();
    for (int t = 512; t > 0; t >>= 1) {
        if (tid < t) red[tid] += red[tid + t];
        __syncthreads();
    }
    if (tid == 0) {
        out[(size_t)NVEC * DIM]     = (float)(0.25 * loss_tot / (double)((size_t)NVEC * DIM));
        out[(size_t)NVEC * DIM + 1] = (float)exp(-red[0]);
    }
}

extern "C" void kernel_launch(void* const* d_in, const int* in_sizes, int n_in,
                              void* d_out, int out_size, void* d_ws, size_t ws_size,
                              hipStream_t stream) {
    const float* inp = (const float*)d_in[0];   // (64,64,64,64) f32
    const float* cb  = (const float*)d_in[1];   // (1024,64) f32
    float* out = (float*)d_out;

    char* ws = (char*)d_ws;
    float*          cnf       = (float*)(ws + 0);
    unsigned short* cbA       = (unsigned short*)(ws + 4096);
    unsigned int*   pbuf      = (unsigned int*)(ws + 135168);
    float*          xnpart    = (float*)(ws + 1183744);
    float*          scorepart = (float*)(ws + 1185792);
    unsigned int*   slots     = (unsigned int*)(ws + 1189888);

    vq_prep<<<dim3(32), dim3(256), 0, stream>>>(cb, cbA, cnf, slots);
    vq_mainA<<<dim3(AGRID), dim3(512), 0, stream>>>(inp, cbA, cnf, pbuf, xnpart);
    vq_mainB<<<dim3(BGRID), dim3(256), 0, stream>>>(pbuf, cb, out, scorepart, slots);
    vq_finalize<<<dim3(1), dim3(1024), 0, stream>>>(out, scorepart, xnpart, slots);
}

// Round 17
// 66.479 us; speedup vs baseline: 1.4126x; 1.4126x over previous
//
#include <hip/hip_runtime.h>

#define NVEC (64*64*64)   // 262144 vectors
#define KCB 1024          // codebook size
#define DIM 64            // codebook dim
#define VB 128            // vectors per batch
#define NBATCH 8          // batches per A-block
#define AGRID 256         // NVEC / (NBATCH*VB)
#define BVEC 256          // vectors per B-block
#define BGRID (NVEC / BVEC)
#define NSLOT 32          // global count-accumulation slots

typedef __attribute__((ext_vector_type(8))) short s16x8;   // 8 x bf16
typedef __attribute__((ext_vector_type(4))) float f32x4;

#define MFMA16(A, B, C) __builtin_amdgcn_mfma_f32_16x16x32_bf16((A), (B), (C), 0, 0, 0)

// ws layout (bytes):
//       0 : float cnf[1024]            (ends 4096)
//    4096 : ushort cbA[64][2][64][8]   A-frag bf16(-2c), 131072 B (ends 135168)
//  135168 : uint pbuf[NVEC]            packed (score|idx), 1 MB (ends 1183744)
// 1183744 : float xnpart[256]          per-A-block sum ||x||^2
// 1185792 : float scorepart[1024]      per-B-block sum min-scores
// 1189888 : uint slots[32][1024]       count accumulators (zeroed by vq_prep)

__global__ __launch_bounds__(256) void vq_prep(const float* __restrict__ cb,
                                               unsigned short* __restrict__ cbA,
                                               float* __restrict__ cnf,
                                               unsigned int* __restrict__ slots) {
    int q = blockIdx.x * 256 + threadIdx.x;      // 0..8191
    ((int4*)slots)[q] = int4{0, 0, 0, 0};         // zero all 32*1024 uints
    int t = q >> 7;
    int h = (q >> 6) & 1;
    int l = q & 63;
    int m = t * 16 + (l & 15);
    int d0 = h * 32 + ((l >> 4) & 3) * 8;
    const float* row = cb + (size_t)m * DIM + d0;
    unsigned short* dst = cbA + (size_t)q * 8;
    #pragma unroll
    for (int j = 0; j < 8; ++j) {
        float f = -2.0f * row[j];
        unsigned u = __float_as_uint(f);
        dst[j] = (unsigned short)((u + 0x7fffu + ((u >> 16) & 1u)) >> 16);  // RNE bf16
    }
    if (q < KCB) {
        const float* r2 = cb + (size_t)q * DIM;
        double s = 0.0;
        for (int d = 0; d < DIM; ++d) { double c = (double)r2[d]; s = fma(c, c, s); }
        cnf[q] = (float)s;
    }
}

// Phase A = R13's lockstep (1024 thr, 16 waves x 64 register-resident codes)
// with the heavy epilogue REMOVED from the barrier loop: per batch we emit only
// one packed u32 per vector. Gather/out-write/hist/score-sum live in phase B.
__global__ __launch_bounds__(1024) void vq_mainA(const float* __restrict__ inp,
                                                 const unsigned short* __restrict__ cbA,
                                                 const float* __restrict__ cnf,
                                                 unsigned int* __restrict__ pbuf,
                                                 float* __restrict__ xnpart) {
    __shared__ unsigned short xf[2][1024][8];  // x B-frags, double-buffered, 32 KB
    __shared__ float sred[VB][17];             // per-vec per-wave packed best, 8.7 KB
    __shared__ float lossL[16];

    const int tid  = threadIdx.x;
    const int lane = tid & 63;
    const int wv   = tid >> 6;        // wave 0..15 = 64-code slice
    const int l15  = lane & 15;
    const int g    = lane >> 4;
    const int gi   = g * 4;
    const size_t blockbase = (size_t)blockIdx.x * (NBATCH * VB);

    // convert role (all 1024 threads): cell tid = (vt*2+h)*64 + l
    const int cvt_vt  = tid >> 7;                        // 0..7
    const int cvt_h   = (tid >> 6) & 1;
    const int cvt_l   = tid & 63;
    const int cvt_vec = cvt_vt * 16 + (cvt_l & 15);      // vec-in-batch 0..127
    const int cvt_d0  = cvt_h * 32 + (cvt_l >> 4) * 8;   // first of its 8 dims

    // ---- issue batch-0 x loads first (longest latency) ----
    float4 x0, x1;
    {
        const float* xp = inp + (blockbase + cvt_vec) * DIM + cvt_d0;
        x0 = ((const float4*)xp)[0];
        x1 = ((const float4*)xp)[1];
    }

    // ---- this wave's 64 codes -> registers (stay forever; proven no-spill) ----
    const s16x8* __restrict__ Ap = (const s16x8*)cbA;
    s16x8 A[4][2];
    f32x4 cn[4];
    #pragma unroll
    for (int tt = 0; tt < 4; ++tt) {
        int T = wv * 4 + tt;
        A[tt][0] = Ap[(T * 2 + 0) * 64 + lane];
        A[tt][1] = Ap[(T * 2 + 1) * 64 + lane];
        cn[tt]   = *(const f32x4*)(cnf + T * 16 + gi);
    }

    float xnacc = 0.0f;

    for (int b = 0; b < NBATCH; ++b) {
        const int buf = b & 1;

        // ---- convert: 8 floats -> one 16B frag cell; accumulate ||x||^2 ----
        {
            float f[8] = {x0.x, x0.y, x0.z, x0.w, x1.x, x1.y, x1.z, x1.w};
            unsigned wq[4];
            #pragma unroll
            for (int p = 0; p < 4; ++p) {
                xnacc = fmaf(f[2*p], f[2*p], xnacc);
                xnacc = fmaf(f[2*p+1], f[2*p+1], xnacc);
                unsigned r;
                asm("v_cvt_pk_bf16_f32 %0, %1, %2" : "=v"(r) : "v"(f[2*p]), "v"(f[2*p+1]));
                wq[p] = r;
            }
            *(int4*)&xf[buf][tid][0] = *(const int4*)wq;
        }
        __syncthreads();   // frags ready

        // ---- issue next batch's x loads; held in regs across MFMA phase ----
        if (b + 1 < NBATCH) {
            const float* xp = inp + (blockbase + (size_t)(b + 1) * VB + cvt_vec) * DIM + cvt_d0;
            x0 = ((const float4*)xp)[0];
            x1 = ((const float4*)xp)[1];
        }

        // ---- MFMA + argmin: this wave scores 128 vecs vs its 64 codes ----
        float bestv[8];
        #pragma unroll
        for (int vt = 0; vt < 8; ++vt) {
            s16x8 xb0 = *(const s16x8*)&xf[buf][(vt * 2 + 0) * 64 + lane][0];
            s16x8 xb1 = *(const s16x8*)&xf[buf][(vt * 2 + 1) * 64 + lane][0];
            f32x4 a0 = cn[0], a1 = cn[1], a2 = cn[2], a3 = cn[3];
            a0 = MFMA16(A[0][0], xb0, a0);
            a1 = MFMA16(A[1][0], xb0, a1);
            a2 = MFMA16(A[2][0], xb0, a2);
            a3 = MFMA16(A[3][0], xb0, a3);
            a0 = MFMA16(A[0][1], xb1, a0);
            a1 = MFMA16(A[1][1], xb1, a1);
            a2 = MFMA16(A[2][1], xb1, a2);
            a3 = MFMA16(A[3][1], xb1, a3);

            float bv = 3.4e38f;
            #define PACKMIN(ACC, TT) {                                                          \
                unsigned cbase = (unsigned)((wv * 4 + (TT)) * 16 + gi);                         \
                float p0 = __uint_as_float((__float_as_uint(ACC[0]) & 0xFFFFFC00u) | cbase);    \
                float p1 = __uint_as_float((__float_as_uint(ACC[1]) & 0xFFFFFC00u) | (cbase+1));\
                float p2 = __uint_as_float((__float_as_uint(ACC[2]) & 0xFFFFFC00u) | (cbase+2));\
                float p3 = __uint_as_float((__float_as_uint(ACC[3]) & 0xFFFFFC00u) | (cbase+3));\
                float m01;                                                                      \
                asm("v_min3_f32 %0, %1, %2, %3" : "=v"(m01) : "v"(p0), "v"(p1), "v"(p2));       \
                asm("v_min3_f32 %0, %1, %2, %3" : "=v"(bv) : "v"(m01), "v"(p3), "v"(bv)); }
            PACKMIN(a0, 0) PACKMIN(a1, 1) PACKMIN(a2, 2) PACKMIN(a3, 3)
            #undef PACKMIN
            bestv[vt] = bv;
        }

        // cross-lane-group combine (codes split across g), publish per-wave best
        #pragma unroll
        for (int vt = 0; vt < 8; ++vt) {
            bestv[vt] = fminf(bestv[vt], __shfl_xor(bestv[vt], 16));
            bestv[vt] = fminf(bestv[vt], __shfl_xor(bestv[vt], 32));
        }
        if (g == 0) {
            #pragma unroll
            for (int vt = 0; vt < 8; ++vt) sred[vt * 16 + l15][wv] = bestv[vt];
        }
        __syncthreads();   // sred ready

        // ---- 16-way reduce -> ONE packed u32 per vector (tiny, fire&forget) ----
        #pragma unroll
        for (int rep = 0; rep < 2; ++rep) {
            const int vec = rep * 64 + (tid >> 4), sl = tid & 15;
            float pb = sred[vec][sl];
            pb = fminf(pb, __shfl_xor(pb, 1));
            pb = fminf(pb, __shfl_xor(pb, 2));
            pb = fminf(pb, __shfl_xor(pb, 4));
            pb = fminf(pb, __shfl_xor(pb, 8));
            if (sl == 0)
                pbuf[blockbase + (size_t)b * VB + vec] = __float_as_uint(pb);
        }
        // next convert writes xf[buf^1]; sred rewritten only after next barrier
    }

    // ---- block Sum ||x||^2 -> one partial (covers every x element once) ----
    #pragma unroll
    for (int off = 32; off > 0; off >>= 1) xnacc += __shfl_xor(xnacc, off);
    if (lane == 0) lossL[wv] = xnacc;
    __syncthreads();
    if (tid == 0) {
        float v = 0.f;
        #pragma unroll
        for (int i = 0; i < 16; ++i) v += lossL[i];
        xnpart[blockIdx.x] = v;
    }
}

// Phase B: streaming -- read packed best, gather code row (L2-hot), write out,
// sum scores, LDS hist -> slots. Pure TLP, no MFMA, no lockstep.
__global__ __launch_bounds__(256) void vq_mainB(const unsigned int* __restrict__ pbuf,
                                                const float* __restrict__ cb,
                                                float* __restrict__ out,
                                                float* __restrict__ scorepart,
                                                unsigned int* __restrict__ slots) {
    __shared__ unsigned int histS[KCB];
    __shared__ float lred[4];
    const int tid = threadIdx.x, lane = tid & 63, wv = tid >> 6;
    #pragma unroll
    for (int i = 0; i < 4; ++i) histS[tid + i * 256] = 0u;
    __syncthreads();

    float sacc = 0.f;
    const size_t vb = (size_t)blockIdx.x * BVEC;
    const float4* cb4 = (const float4*)cb;
    float4* out4 = (float4*)out;

    for (int r = 0; r < BVEC / 16; ++r) {
        const size_t vec = vb + r * 16 + (tid >> 4);
        const int sl = tid & 15;
        float pf = __uint_as_float(pbuf[vec]);       // final packed (score|idx)
        const int bk = (int)(__float_as_uint(pf) & 1023u);
        float4 q = cb4[bk * 16 + sl];
        out4[vec * 16 + sl] = q;
        if (sl == 0) {
            sacc += pf;                               // idx-bit noise ~2e-6 rel
            atomicAdd(&histS[bk], 1u);
        }
    }

    #pragma unroll
    for (int off = 32; off > 0; off >>= 1) sacc += __shfl_xor(sacc, off);
    if (lane == 0) lred[wv] = sacc;
    __syncthreads();
    if (tid == 0) scorepart[blockIdx.x] = lred[0] + lred[1] + lred[2] + lred[3];
    #pragma unroll
    for (int i = 0; i < 4; ++i) {
        unsigned hv = histS[tid + i * 256];
        if (hv) atomicAdd(&slots[(blockIdx.x & (NSLOT - 1)) * KCB + tid + i * 256], hv);
    }
}

__global__ __launch_bounds__(1024) void vq_finalize(float* __restrict__ out,
                                                    const float* __restrict__ scorepart,
                                                    const float* __restrict__ xnpart,
                                                    const unsigned int* __restrict__ slots) {
    __shared__ double red[1024];
    const int tid = threadIdx.x;
    unsigned tot = 0;
    #pragma unroll
    for (int s = 0; s < NSLOT; ++s) tot += slots[s * KCB + tid];
    double p = (double)tot / (double)NVEC;
    double h = p * log(p + 1e-10);
    double ls = (double)scorepart[tid] + (tid < AGRID ? (double)xnpart[tid] : 0.0);

    red[tid] = ls;
    __syncthreads();
    for (int t = 512; t > 0; t >>= 1) {
        if (tid < t) red[tid] += red[tid + t];
        __syncthreads();
    }
    double loss_tot = red[0];
    __syncthreads();
    red[tid] = h;
    __syncthreads();
    for (int t = 512; t > 0; t >>= 1) {
        if (tid < t) red[tid] += red[tid + t];
        __syncthreads();
    }
    if (tid == 0) {
        out[(size_t)NVEC * DIM]     = (float)(0.25 * loss_tot / (double)((size_t)NVEC * DIM));
        out[(size_t)NVEC * DIM + 1] = (float)exp(-red[0]);
    }
}

extern "C" void kernel_launch(void* const* d_in, const int* in_sizes, int n_in,
                              void* d_out, int out_size, void* d_ws, size_t ws_size,
                              hipStream_t stream) {
    const float* inp = (const float*)d_in[0];   // (64,64,64,64) f32
    const float* cb  = (const float*)d_in[1];   // (1024,64) f32
    float* out = (float*)d_out;

    char* ws = (char*)d_ws;
    float*          cnf       = (float*)(ws + 0);
    unsigned short* cbA       = (unsigned short*)(ws + 4096);
    unsigned int*   pbuf      = (unsigned int*)(ws + 135168);
    float*          xnpart    = (float*)(ws + 1183744);
    float*          scorepart = (float*)(ws + 1185792);
    unsigned int*   slots     = (unsigned int*)(ws + 1189888);

    vq_prep<<<dim3(32), dim3(256), 0, stream>>>(cb, cbA, cnf, slots);
    vq_mainA<<<dim3(AGRID), dim3(1024), 0, stream>>>(inp, cbA, cnf, pbuf, xnpart);
    vq_mainB<<<dim3(BGRID), dim3(256), 0, stream>>>(pbuf, cb, out, scorepart, slots);
    vq_finalize<<<dim3(1), dim3(1024), 0, stream>>>(out, scorepart, xnpart, slots);
}

// Round 18
// 58.230 us; speedup vs baseline: 1.6128x; 1.1417x over previous
//
#include <hip/hip_runtime.h>

#define NVEC (64*64*64)   // 262144 vectors
#define KCB 1024          // codebook size
#define DIM 64            // codebook dim
#define VB 128            // vectors per batch
#define BATCHES 8         // batches per block
#define GRID 256          // NVEC / (BATCHES*VB)
#define NSLOT 32          // global count-accumulation slots

typedef __attribute__((ext_vector_type(8))) short s16x8;   // 8 x bf16
typedef __attribute__((ext_vector_type(4))) float f32x4;

#define MFMA16(A, B, C) __builtin_amdgcn_mfma_f32_16x16x32_bf16((A), (B), (C), 0, 0, 0)

// Barrier that drains ONLY LDS (lgkmcnt) -- global stores/loads stay in
// flight across it (T4 counted-vmcnt pattern; hipcc's __syncthreads would
// emit s_waitcnt vmcnt(0) and serialize the epilogue stores every batch).
#define LDS_BARRIER()                                        \
    do {                                                     \
        asm volatile("s_waitcnt lgkmcnt(0)" ::: "memory");   \
        __builtin_amdgcn_s_barrier();                        \
        asm volatile("" ::: "memory");                       \
    } while (0)

// ws layout (bytes):
//      0 : float cnf[1024]                  (ends 4096)
//   4096 : ushort cbA[64][2][64][8]         A-frag bf16(-2c), 131072 B (ends 135168)
// 135168 : float block_partials[256]        (ends 136192) -- per-block loss
// 137216 : uint slots[32][1024]             (ends 268288) -- count accumulators,
//                                           zeroed by vq_prep, 8 RMW/addr only

__global__ __launch_bounds__(256) void vq_prep(const float* __restrict__ cb,
                                               unsigned short* __restrict__ cbA,
                                               float* __restrict__ cnf,
                                               unsigned int* __restrict__ slots) {
    int q = blockIdx.x * 256 + threadIdx.x;      // 0..8191
    ((int4*)slots)[q] = int4{0, 0, 0, 0};         // zero all 32*1024 uints
    int t = q >> 7;
    int h = (q >> 6) & 1;
    int l = q & 63;
    int m = t * 16 + (l & 15);
    int d0 = h * 32 + ((l >> 4) & 3) * 8;
    const float* row = cb + (size_t)m * DIM + d0;
    unsigned short* dst = cbA + (size_t)q * 8;
    #pragma unroll
    for (int j = 0; j < 8; ++j) {
        float f = -2.0f * row[j];
        unsigned u = __float_as_uint(f);
        dst[j] = (unsigned short)((u + 0x7fffu + ((u >> 16) & 1u)) >> 16);  // RNE bf16
    }
    if (q < KCB) {
        const float* r2 = cb + (size_t)q * DIM;
        double s = 0.0;
        for (int d = 0; d < DIM; ++d) { double c = (double)r2[d]; s = fma(c, c, s); }
        cnf[q] = (float)s;
    }
}

// R13 structure (fused epilogue), single change: LDS-only barriers so the
// per-batch out-stores/gathers overlap the next batch's convert+MFMA.
__global__ __launch_bounds__(1024) void vq_main(const float* __restrict__ inp,
                                                const unsigned short* __restrict__ cbA,
                                                const float* __restrict__ cnf,
                                                const float* __restrict__ cb,
                                                float* __restrict__ out,
                                                float* __restrict__ partials,
                                                unsigned int* __restrict__ slots) {
    __shared__ unsigned short xf[2][1024][8];  // x B-frags, double-buffered, 32 KB
    __shared__ float xnp[2][1024];             // xnorm partials, 8 KB
    __shared__ float sred[VB][17];             // per-vec per-wave packed best, 8.5 KB
    __shared__ unsigned int histS[KCB];        // per-block count histogram, 4 KB
    __shared__ float lossL[64];

    const int tid  = threadIdx.x;
    const int lane = tid & 63;
    const int wv   = tid >> 6;        // wave 0..15 = code slice
    const int l15  = lane & 15;
    const int g    = lane >> 4;
    const int gi   = g * 4;
    const int blockbase = blockIdx.x * (BATCHES * VB);

    // convert-role constants (ALL 1024 threads): cell tid = (vt*2+h)*64 + l
    const int cvt_vt    = tid >> 7;                          // 0..7
    const int cvt_h     = (tid >> 6) & 1;
    const int cvt_l     = tid & 63;
    const int cvt_vec   = cvt_vt * 16 + (cvt_l & 15);        // vec-in-batch 0..127
    const int cvt_d0    = cvt_h * 32 + (cvt_l >> 4) * 8;     // first of 8 dims
    const int cvt_slice = cvt_h * 4 + (cvt_l >> 4);          // 0..7

    histS[tid] = 0u;   // ordered before first use by the first barrier

    // ---- issue batch-0 x loads first (longest latency) ----
    float4 x0, x1;
    {
        const float* xp = inp + (size_t)(blockbase + cvt_vec) * DIM + cvt_d0;
        x0 = ((const float4*)xp)[0];
        x1 = ((const float4*)xp)[1];
    }

    // ---- load this wave's codebook slice into registers (stays forever) ----
    const s16x8* __restrict__ Ap = (const s16x8*)cbA;
    s16x8 A[4][2];
    f32x4 cn[4];
    #pragma unroll
    for (int tt = 0; tt < 4; ++tt) {
        int T = wv * 4 + tt;
        A[tt][0] = Ap[(T * 2 + 0) * 64 + lane];
        A[tt][1] = Ap[(T * 2 + 1) * 64 + lane];
        cn[tt]   = *(const f32x4*)(cnf + T * 16 + gi);
    }

    float loss_acc = 0.0f;

    for (int b = 0; b < BATCHES; ++b) {
        const int buf = b & 1;
        const int vecbase = blockbase + b * VB;

        // ---- convert phase (all threads): x regs -> bf16 frags in LDS ----
        {
            float f[8] = {x0.x, x0.y, x0.z, x0.w, x1.x, x1.y, x1.z, x1.w};
            float xn = 0.f;
            unsigned wq[4];
            #pragma unroll
            for (int p = 0; p < 4; ++p) {
                xn = fmaf(f[2*p], f[2*p], xn);
                xn = fmaf(f[2*p+1], f[2*p+1], xn);
                unsigned r;
                asm("v_cvt_pk_bf16_f32 %0, %1, %2" : "=v"(r) : "v"(f[2*p]), "v"(f[2*p+1]));
                wq[p] = r;
            }
            *(int4*)&xf[buf][tid][0] = *(const int4*)wq;
            xnp[buf][cvt_vec * 8 + cvt_slice] = xn;
        }
        LDS_BARRIER();   // frags ready; global stores from prev epilogue stay in flight

        // ---- issue next batch's x loads; held in regs across MFMA phase ----
        if (b + 1 < BATCHES) {
            const float* xp = inp + (size_t)(vecbase + VB + cvt_vec) * DIM + cvt_d0;
            x0 = ((const float4*)xp)[0];
            x1 = ((const float4*)xp)[1];
        }

        // ---- MFMA + argmin: this wave scores 128 vecs vs its 64 codes ----
        float bestv[8];
        #pragma unroll
        for (int vt = 0; vt < 8; ++vt) {
            s16x8 xb0 = *(const s16x8*)&xf[buf][(vt * 2 + 0) * 64 + lane][0];
            s16x8 xb1 = *(const s16x8*)&xf[buf][(vt * 2 + 1) * 64 + lane][0];
            f32x4 a0 = cn[0], a1 = cn[1], a2 = cn[2], a3 = cn[3];
            a0 = MFMA16(A[0][0], xb0, a0);
            a1 = MFMA16(A[1][0], xb0, a1);
            a2 = MFMA16(A[2][0], xb0, a2);
            a3 = MFMA16(A[3][0], xb0, a3);
            a0 = MFMA16(A[0][1], xb1, a0);
            a1 = MFMA16(A[1][1], xb1, a1);
            a2 = MFMA16(A[2][1], xb1, a2);
            a3 = MFMA16(A[3][1], xb1, a3);

            float bv = 3.4e38f;
            // packed argmin: 4 v_and_or + 2 v_min3 per quad
            #define PACKMIN(ACC, TT) {                                                        \
                unsigned cbase = (unsigned)(wv * 64 + (TT) * 16 + gi);                        \
                float p0 = __uint_as_float((__float_as_uint(ACC[0]) & 0xFFFFFC00u) | cbase);  \
                float p1 = __uint_as_float((__float_as_uint(ACC[1]) & 0xFFFFFC00u) | (cbase+1));\
                float p2 = __uint_as_float((__float_as_uint(ACC[2]) & 0xFFFFFC00u) | (cbase+2));\
                float p3 = __uint_as_float((__float_as_uint(ACC[3]) & 0xFFFFFC00u) | (cbase+3));\
                float m01;                                                                    \
                asm("v_min3_f32 %0, %1, %2, %3" : "=v"(m01) : "v"(p0), "v"(p1), "v"(p2));     \
                asm("v_min3_f32 %0, %1, %2, %3" : "=v"(bv) : "v"(m01), "v"(p3), "v"(bv)); }
            PACKMIN(a0, 0) PACKMIN(a1, 1) PACKMIN(a2, 2) PACKMIN(a3, 3)
            #undef PACKMIN
            bestv[vt] = bv;
        }

        // cross-lane-group combine (codes split across g), publish per-wave best
        #pragma unroll
        for (int vt = 0; vt < 8; ++vt) {
            bestv[vt] = fminf(bestv[vt], __shfl_xor(bestv[vt], 16));
            bestv[vt] = fminf(bestv[vt], __shfl_xor(bestv[vt], 32));
        }
        if (g == 0) {
            #pragma unroll
            for (int vt = 0; vt < 8; ++vt) sred[vt * 16 + l15][wv] = bestv[vt];
        }
        LDS_BARRIER();   // sred ready; epilogue stores still unfenced

        // ---- final 16-way reduce + coalesced epilogue (2 reps x 64 vecs) ----
        #pragma unroll
        for (int rep = 0; rep < 2; ++rep) {
            const int vec = rep * 64 + (tid >> 4), sl = tid & 15;
            float pb = sred[vec][sl];
            pb = fminf(pb, __shfl_xor(pb, 1));
            pb = fminf(pb, __shfl_xor(pb, 2));
            pb = fminf(pb, __shfl_xor(pb, 4));
            pb = fminf(pb, __shfl_xor(pb, 8));
            int bk = (int)(__float_as_uint(pb) & 1023u);
            float4 q = ((const float4*)cb)[bk * 16 + sl];
            ((float4*)out)[(size_t)(vecbase + vec) * 16 + sl] = q;
            if (sl == 0) {
                float xn = 0.f;
                #pragma unroll
                for (int j = 0; j < 8; ++j) xn += xnp[buf][vec * 8 + j];
                loss_acc += pb + xn;               // min dist = packed score + ||x||^2
                atomicAdd(&histS[bk], 1u);         // LDS atomic (lgkm-covered)
            }
        }
        // next convert writes xf/xnp[buf^1]; sred rewritten only after the next
        // frags-ready barrier; out-stores drain lazily under later compute.
    }

    // ---- block loss reduction + histogram fold-out ----
    if ((tid & 15) == 0) lossL[tid >> 4] = loss_acc;
    __syncthreads();
    if (tid < 64) {
        float v = lossL[tid];
        #pragma unroll
        for (int off = 32; off > 0; off >>= 1) v += __shfl_xor(v, off);
        if (tid == 0) partials[blockIdx.x] = v;
    }
    unsigned hv = histS[tid];
    if (hv) atomicAdd(&slots[(blockIdx.x & (NSLOT - 1)) * KCB + tid], hv);
}

__global__ __launch_bounds__(1024) void vq_finalize(float* __restrict__ out,
                                                    const float* __restrict__ partials,
                                                    const unsigned int* __restrict__ slots) {
    __shared__ double red[1024];
    const int tid = threadIdx.x;
    unsigned tot = 0;
    #pragma unroll
    for (int s = 0; s < NSLOT; ++s) tot += slots[s * KCB + tid];
    double p = (double)tot / (double)NVEC;
    double h = p * log(p + 1e-10);
    double ls = (tid < GRID) ? (double)partials[tid] : 0.0;

    red[tid] = ls;
    __syncthreads();
    for (int t = 512; t > 0; t >>= 1) {
        if (tid < t) red[tid] += red[tid + t];
        __syncthreads();
    }
    double loss_tot = red[0];
    __syncthreads();
    red[tid] = h;
    __syncthreads();
    for (int t = 512; t > 0; t >>= 1) {
        if (tid < t) red[tid] += red[tid + t];
        __syncthreads();
    }
    if (tid == 0) {
        out[(size_t)NVEC * DIM]     = (float)(0.25 * loss_tot / (double)((size_t)NVEC * DIM));
        out[(size_t)NVEC * DIM + 1] = (float)exp(-red[0]);
    }
}

extern "C" void kernel_launch(void* const* d_in, const int* in_sizes, int n_in,
                              void* d_out, int out_size, void* d_ws, size_t ws_size,
                              hipStream_t stream) {
    const float* inp = (const float*)d_in[0];   // (64,64,64,64) f32
    const float* cb  = (const float*)d_in[1];   // (1024,64) f32
    float* out = (float*)d_out;

    char* ws = (char*)d_ws;
    float*          cnf      = (float*)(ws + 0);
    unsigned short* cbA      = (unsigned short*)(ws + 4096);
    float*          partials = (float*)(ws + 135168);
    unsigned int*   slots    = (unsigned int*)(ws + 137216);

    vq_prep<<<dim3(32), dim3(256), 0, stream>>>(cb, cbA, cnf, slots);
    vq_main<<<dim3(GRID), dim3(1024), 0, stream>>>(inp, cbA, cnf, cb, out,
                                                   partials, slots);
    vq_finalize<<<dim3(1), dim3(1024), 0, stream>>>(out, partials, slots);
}

// Round 19
// 56.409 us; speedup vs baseline: 1.6648x; 1.0323x over previous
//
#include <hip/hip_runtime.h>

#define NVEC (64*64*64)   // 262144 vectors
#define KCB 1024          // codebook size
#define DIM 64            // codebook dim
#define VB 128            // vectors per batch
#define BATCHES 8         // batches per block
#define GRID 256          // NVEC / (BATCHES*VB)
#define NSLOT 32          // global count-accumulation slots

typedef __attribute__((ext_vector_type(8))) short s16x8;   // 8 x bf16
typedef __attribute__((ext_vector_type(4))) float f32x4;

#define MFMA16(A, B, C) __builtin_amdgcn_mfma_f32_16x16x32_bf16((A), (B), (C), 0, 0, 0)

// LDS-only barrier: global stores/gathers stay in flight across it.
#define LDS_BARRIER()                                        \
    do {                                                     \
        asm volatile("s_waitcnt lgkmcnt(0)" ::: "memory");   \
        __builtin_amdgcn_s_barrier();                        \
        asm volatile("" ::: "memory");                       \
    } while (0)

// ws layout (bytes):
//      0 : float cnf[1024]                  (ends 4096)
//   4096 : ushort cbA[64][2][64][8]         A-frag bf16(-2c), 131072 B (ends 135168)
// 135168 : float block_partials[256]        (ends 136192) -- per-block loss
// 137216 : uint slots[32][1024]             (ends 268288) -- count accumulators

__global__ __launch_bounds__(256) void vq_prep(const float* __restrict__ cb,
                                               unsigned short* __restrict__ cbA,
                                               float* __restrict__ cnf,
                                               unsigned int* __restrict__ slots) {
    int q = blockIdx.x * 256 + threadIdx.x;      // 0..8191
    ((int4*)slots)[q] = int4{0, 0, 0, 0};         // zero all 32*1024 uints
    int t = q >> 7;
    int h = (q >> 6) & 1;
    int l = q & 63;
    int m = t * 16 + (l & 15);
    int d0 = h * 32 + ((l >> 4) & 3) * 8;
    const float* row = cb + (size_t)m * DIM + d0;
    unsigned short* dst = cbA + (size_t)q * 8;
    #pragma unroll
    for (int j = 0; j < 8; ++j) {
        float f = -2.0f * row[j];
        unsigned u = __float_as_uint(f);
        dst[j] = (unsigned short)((u + 0x7fffu + ((u >> 16) & 1u)) >> 16);  // RNE bf16
    }
    if (q < KCB) {
        const float* r2 = cb + (size_t)q * DIM;
        double s = 0.0;
        for (int d = 0; d < DIM; ++d) { double c = (double)r2[d]; s = fma(c, c, s); }
        cnf[q] = (float)s;
    }
}

// ONE barrier per batch: {sred[b], xf[b+1]} published together; epilogue(b)
// runs in the same barrier-free run as MFMA(b+1) -> gather/store latency
// hides under matrix work; waves decorrelate over the long run.
__global__ __launch_bounds__(1024) void vq_main(const float* __restrict__ inp,
                                                const unsigned short* __restrict__ cbA,
                                                const float* __restrict__ cnf,
                                                const float* __restrict__ cb,
                                                float* __restrict__ out,
                                                float* __restrict__ partials,
                                                unsigned int* __restrict__ slots) {
    __shared__ unsigned short xf[2][1024][8];  // x B-frags, dbuf, 32 KB
    __shared__ float xnp[2][1024];             // xnorm partials, dbuf, 8 KB
    __shared__ float sred[2][VB][17];          // packed best, dbuf, 17.4 KB
    __shared__ unsigned int histS[KCB];        // per-block count histogram, 4 KB
    __shared__ float lossL[64];

    const int tid  = threadIdx.x;
    const int lane = tid & 63;
    const int wv   = tid >> 6;        // wave 0..15 = 64-code slice
    const int l15  = lane & 15;
    const int g    = lane >> 4;
    const int gi   = g * 4;
    const int blockbase = blockIdx.x * (BATCHES * VB);

    // convert-role constants: cell tid = (vt*2+h)*64 + l
    const int cvt_vt    = tid >> 7;
    const int cvt_h     = (tid >> 6) & 1;
    const int cvt_l     = tid & 63;
    const int cvt_vec   = cvt_vt * 16 + (cvt_l & 15);        // vec-in-batch 0..127
    const int cvt_d0    = cvt_h * 32 + (cvt_l >> 4) * 8;
    const int cvt_slice = cvt_h * 4 + (cvt_l >> 4);          // 0..7

    // epilogue role: 8 threads per vector
    const int evec = tid >> 3;        // 0..127
    const int sl8  = tid & 7;

    histS[tid] = 0u;

    // ---- batch-0 x loads ----
    float4 x0, x1;
    {
        const float* xp = inp + (size_t)(blockbase + cvt_vec) * DIM + cvt_d0;
        x0 = ((const float4*)xp)[0];
        x1 = ((const float4*)xp)[1];
    }

    // ---- this wave's 64 codes -> registers (stay forever) ----
    const s16x8* __restrict__ Ap = (const s16x8*)cbA;
    s16x8 A[4][2];
    f32x4 cn[4];
    #pragma unroll
    for (int tt = 0; tt < 4; ++tt) {
        int T = wv * 4 + tt;
        A[tt][0] = Ap[(T * 2 + 0) * 64 + lane];
        A[tt][1] = Ap[(T * 2 + 1) * 64 + lane];
        cn[tt]   = *(const f32x4*)(cnf + T * 16 + gi);
    }

    // ---- prologue: convert batch 0 ----
    {
        float f[8] = {x0.x, x0.y, x0.z, x0.w, x1.x, x1.y, x1.z, x1.w};
        float xn = 0.f;
        unsigned wq[4];
        #pragma unroll
        for (int p = 0; p < 4; ++p) {
            xn = fmaf(f[2*p], f[2*p], xn);
            xn = fmaf(f[2*p+1], f[2*p+1], xn);
            unsigned r;
            asm("v_cvt_pk_bf16_f32 %0, %1, %2" : "=v"(r) : "v"(f[2*p]), "v"(f[2*p+1]));
            wq[p] = r;
        }
        *(int4*)&xf[0][tid][0] = *(const int4*)wq;
        xnp[0][cvt_vec * 8 + cvt_slice] = xn;
    }
    LDS_BARRIER();

    float loss_acc = 0.0f;

    for (int b = 0; b < BATCHES; ++b) {
        const int buf = b & 1;
        const int vecbase = blockbase + b * VB;

        // ---- issue next batch's x loads ----
        if (b + 1 < BATCHES) {
            const float* xp = inp + (size_t)(vecbase + VB + cvt_vec) * DIM + cvt_d0;
            x0 = ((const float4*)xp)[0];
            x1 = ((const float4*)xp)[1];
        }

        // ---- MFMA + argmin: this wave scores 128 vecs vs its 64 codes ----
        __builtin_amdgcn_s_setprio(1);
        float bestv[8];
        #pragma unroll
        for (int vt = 0; vt < 8; ++vt) {
            s16x8 xb0 = *(const s16x8*)&xf[buf][(vt * 2 + 0) * 64 + lane][0];
            s16x8 xb1 = *(const s16x8*)&xf[buf][(vt * 2 + 1) * 64 + lane][0];
            f32x4 a0 = cn[0], a1 = cn[1], a2 = cn[2], a3 = cn[3];
            a0 = MFMA16(A[0][0], xb0, a0);
            a1 = MFMA16(A[1][0], xb0, a1);
            a2 = MFMA16(A[2][0], xb0, a2);
            a3 = MFMA16(A[3][0], xb0, a3);
            a0 = MFMA16(A[0][1], xb1, a0);
            a1 = MFMA16(A[1][1], xb1, a1);
            a2 = MFMA16(A[2][1], xb1, a2);
            a3 = MFMA16(A[3][1], xb1, a3);

            float bv = 3.4e38f;
            #define PACKMIN(ACC, TT) {                                                        \
                unsigned cbase = (unsigned)(wv * 64 + (TT) * 16 + gi);                        \
                float p0 = __uint_as_float((__float_as_uint(ACC[0]) & 0xFFFFFC00u) | cbase);  \
                float p1 = __uint_as_float((__float_as_uint(ACC[1]) & 0xFFFFFC00u) | (cbase+1));\
                float p2 = __uint_as_float((__float_as_uint(ACC[2]) & 0xFFFFFC00u) | (cbase+2));\
                float p3 = __uint_as_float((__float_as_uint(ACC[3]) & 0xFFFFFC00u) | (cbase+3));\
                float m01;                                                                    \
                asm("v_min3_f32 %0, %1, %2, %3" : "=v"(m01) : "v"(p0), "v"(p1), "v"(p2));     \
                asm("v_min3_f32 %0, %1, %2, %3" : "=v"(bv) : "v"(m01), "v"(p3), "v"(bv)); }
            PACKMIN(a0, 0) PACKMIN(a1, 1) PACKMIN(a2, 2) PACKMIN(a3, 3)
            #undef PACKMIN
            bestv[vt] = bv;
        }
        __builtin_amdgcn_s_setprio(0);

        // ---- combine lane groups, publish sred[buf] ----
        #pragma unroll
        for (int vt = 0; vt < 8; ++vt) {
            bestv[vt] = fminf(bestv[vt], __shfl_xor(bestv[vt], 16));
            bestv[vt] = fminf(bestv[vt], __shfl_xor(bestv[vt], 32));
        }
        if (g == 0) {
            #pragma unroll
            for (int vt = 0; vt < 8; ++vt) sred[buf][vt * 16 + l15][wv] = bestv[vt];
        }

        // ---- pre-read xnorm partial for epilogue (stable since last barrier);
        //      8-lane shfl sum -> lane sl8==0 holds vec evec's ||x||^2 ----
        float xn_reg = xnp[buf][tid];
        xn_reg += __shfl_xor(xn_reg, 1);
        xn_reg += __shfl_xor(xn_reg, 2);
        xn_reg += __shfl_xor(xn_reg, 4);

        // ---- convert next batch (x regs already loaded) ----
        if (b + 1 < BATCHES) {
            float f[8] = {x0.x, x0.y, x0.z, x0.w, x1.x, x1.y, x1.z, x1.w};
            float xn = 0.f;
            unsigned wq[4];
            #pragma unroll
            for (int p = 0; p < 4; ++p) {
                xn = fmaf(f[2*p], f[2*p], xn);
                xn = fmaf(f[2*p+1], f[2*p+1], xn);
                unsigned r;
                asm("v_cvt_pk_bf16_f32 %0, %1, %2" : "=v"(r) : "v"(f[2*p]), "v"(f[2*p+1]));
                wq[p] = r;
            }
            *(int4*)&xf[buf ^ 1][tid][0] = *(const int4*)wq;
            xnp[buf ^ 1][cvt_vec * 8 + cvt_slice] = xn;
        }

        LDS_BARRIER();   // publishes sred[buf] + xf/xnp[buf^1] together

        // ---- epilogue(b): overlaps next iteration's MFMA in the same run ----
        {
            float pb = fminf(sred[buf][evec][sl8], sred[buf][evec][sl8 + 8]);
            pb = fminf(pb, __shfl_xor(pb, 1));
            pb = fminf(pb, __shfl_xor(pb, 2));
            pb = fminf(pb, __shfl_xor(pb, 4));
            int bk = (int)(__float_as_uint(pb) & 1023u);
            const float4* cr = (const float4*)cb + (size_t)bk * 16;
            float4 q0 = cr[sl8];
            float4 q1 = cr[sl8 + 8];
            float4* ov = (float4*)out + (size_t)(vecbase + evec) * 16;
            ov[sl8]     = q0;
            ov[sl8 + 8] = q1;
            if (sl8 == 0) {
                loss_acc += pb + xn_reg;           // min dist = score + ||x||^2
                atomicAdd(&histS[bk], 1u);         // LDS atomic
            }
        }
    }

    // ---- block loss reduction + histogram fold-out ----
    if ((tid & 7) == 0) lossL[tid >> 4] = 0.f;   // init not needed; direct path below
    __syncthreads();
    // lanes with sl8==0 hold per-vec loss contributions in loss_acc
    float lw = loss_acc;
    #pragma unroll
    for (int off = 32; off > 0; off >>= 1) lw += __shfl_xor(lw, off);
    if (lane == 0) lossL[wv] = lw;
    __syncthreads();
    if (tid == 0) {
        float v = 0.f;
        #pragma unroll
        for (int i = 0; i < 16; ++i) v += lossL[i];
        partials[blockIdx.x] = v;
    }
    unsigned hv = histS[tid];
    if (hv) atomicAdd(&slots[(blockIdx.x & (NSLOT - 1)) * KCB + tid], hv);
}

__global__ __launch_bounds__(1024) void vq_finalize(float* __restrict__ out,
                                                    const float* __restrict__ partials,
                                                    const unsigned int* __restrict__ slots) {
    __shared__ double red[1024];
    const int tid = threadIdx.x;
    unsigned tot = 0;
    #pragma unroll
    for (int s = 0; s < NSLOT; ++s) tot += slots[s * KCB + tid];
    double p = (double)tot / (double)NVEC;
    double h = p * log(p + 1e-10);
    double ls = (tid < GRID) ? (double)partials[tid] : 0.0;

    red[tid] = ls;
    __syncthreads();
    for (int t = 512; t > 0; t >>= 1) {
        if (tid < t) red[tid] += red[tid + t];
        __syncthreads();
    }
    double loss_tot = red[0];
    __syncthreads();
    red[tid] = h;
    __syncthreads();
    for (int t = 512; t > 0; t >>= 1) {
        if (tid < t) red[tid] += red[tid + t];
        __syncthreads();
    }
    if (tid == 0) {
        out[(size_t)NVEC * DIM]     = (float)(0.25 * loss_tot / (double)((size_t)NVEC * DIM));
        out[(size_t)NVEC * DIM + 1] = (float)exp(-red[0]);
    }
}

extern "C" void kernel_launch(void* const* d_in, const int* in_sizes, int n_in,
                              void* d_out, int out_size, void* d_ws, size_t ws_size,
                              hipStream_t stream) {
    const float* inp = (const float*)d_in[0];   // (64,64,64,64) f32
    const float* cb  = (const float*)d_in[1];   // (1024,64) f32
    float* out = (float*)d_out;

    char* ws = (char*)d_ws;
    float*          cnf      = (float*)(ws + 0);
    unsigned short* cbA      = (unsigned short*)(ws + 4096);
    float*          partials = (float*)(ws + 135168);
    unsigned int*   slots    = (unsigned int*)(ws + 137216);

    vq_prep<<<dim3(32), dim3(256), 0, stream>>>(cb, cbA, cnf, slots);
    vq_main<<<dim3(GRID), dim3(1024), 0, stream>>>(inp, cbA, cnf, cb, out,
                                                   partials, slots);
    vq_finalize<<<dim3(1), dim3(1024), 0, stream>>>(out, partials, slots);
}